// Round 3
// baseline (169.015 us; speedup 1.0000x reference)
//
#include <hip/hip_runtime.h>

#define NUM_ROI 148
#define NQ 5
#define NN 131072
#define ROI_PER 4                       // ROIs per block
#define NBLK_Y (NUM_ROI / ROI_PER)      // 37
#define NBLK_X (NN / (256 * 4))         // 128

typedef float vf4 __attribute__((ext_vector_type(4)));

// fillBuffer-shaped store streamer: 4736 blocks (~18/CU), each thread owns
// 4 consecutive n and loops 4 ROIs. Weights are wave-uniform (indexed by
// blockIdx.y only) -> scalar s_load broadcast. Outputs stored nontemporal so
// the 37x-reread Z/X stay L2-resident.
__global__ __launch_bounds__(256) void coconet_kernel(
    const float* __restrict__ X, const float* __restrict__ Z,
    const float* __restrict__ Wr, const float* __restrict__ br,
    const float* __restrict__ Wf, const float* __restrict__ bf,
    float* __restrict__ out)
{
    const int tid = threadIdx.x;
    const int n0 = (blockIdx.x * 256 + tid) * 4;
    const int r0 = blockIdx.y * ROI_PER;

    // X[n0..n0+3]
    const vf4 x4 = *reinterpret_cast<const vf4*>(X + n0);
    const float x[4] = {x4.x, x4.y, x4.z, x4.w};

    // Z rows n0..n0+3: 20 contiguous floats at n0*5 (16B aligned, n0%4==0)
    float z[4][NQ];
    {
        const vf4* zp = reinterpret_cast<const vf4*>(Z + (size_t)n0 * NQ);
        const vf4 a = zp[0], b = zp[1], c = zp[2], d = zp[3], e = zp[4];
        const float tmp[20] = {a.x, a.y, a.z, a.w, b.x, b.y, b.z, b.w,
                               c.x, c.y, c.z, c.w, d.x, d.y, d.z, d.w,
                               e.x, e.y, e.z, e.w};
        #pragma unroll
        for (int j = 0; j < 4; ++j)
            #pragma unroll
            for (int q = 0; q < NQ; ++q) z[j][q] = tmp[j * NQ + q];
    }

    float* outR = out + (size_t)r0 * NN + n0;
    float* outF = out + (size_t)(NUM_ROI + r0) * NN + n0;

    #pragma unroll
    for (int i = 0; i < ROI_PER; ++i) {
        const int r = r0 + i;
        // Wave-uniform -> scalar loads
        float wr[NQ], wf[NQ];
        #pragma unroll
        for (int q = 0; q < NQ; ++q) wr[q] = Wr[r * NQ + q];
        const float brv = br[r];
        const float wfx = Wf[r * 6 + 0];
        #pragma unroll
        for (int q = 0; q < NQ; ++q) wf[q] = Wf[r * 6 + 1 + q];
        const float bfv = bf[r];

        float rr[4], ff[4];
        #pragma unroll
        for (int j = 0; j < 4; ++j) {
            float r_ = brv;
            float f_ = fmaf(x[j], wfx, bfv);
            #pragma unroll
            for (int q = 0; q < NQ; ++q) {
                r_ = fmaf(z[j][q], wr[q], r_);
                f_ = fmaf(z[j][q], wf[q], f_);
            }
            rr[j] = r_;
            ff[j] = f_;
        }
        vf4 rv; rv.x = rr[0]; rv.y = rr[1]; rv.z = rr[2]; rv.w = rr[3];
        vf4 fv; fv.x = ff[0]; fv.y = ff[1]; fv.z = ff[2]; fv.w = ff[3];
        __builtin_nontemporal_store(rv, reinterpret_cast<vf4*>(outR + (size_t)i * NN));
        __builtin_nontemporal_store(fv, reinterpret_cast<vf4*>(outF + (size_t)i * NN));
    }
}

extern "C" void kernel_launch(void* const* d_in, const int* in_sizes, int n_in,
                              void* d_out, int out_size, void* d_ws, size_t ws_size,
                              hipStream_t stream) {
    const float* X  = (const float*)d_in[0];
    const float* Z  = (const float*)d_in[1];
    const float* Wr = (const float*)d_in[2];
    const float* br = (const float*)d_in[3];
    const float* Wf = (const float*)d_in[4];
    const float* bf = (const float*)d_in[5];
    float* out = (float*)d_out;

    dim3 grid(NBLK_X, NBLK_Y);  // 128 x 37 = 4736 blocks
    coconet_kernel<<<grid, 256, 0, stream>>>(X, Z, Wr, br, Wf, bf, out);
}